// Round 4
// baseline (52.533 us; speedup 1.0000x reference)
//
#include <hip/hip_runtime.h>
#include <hip/hip_bf16.h>

#define B 256
#define N 2048
#define D 128
#define P 2048
#define C 10
#define S_CHUNKS 8             // blocks per batch in pair kernel
#define PPB (P / S_CHUNKS)     // 256 pairs per block
#define NIT (PPB / 16)         // 16 iterations per wave
#define LN_EPS 1e-5f
#define NORM_EPS 1e-12f

typedef float v2f __attribute__((ext_vector_type(2)));

// ---- packed fp32 VOP3P helpers (CDNA full-rate packed math) ----------------
__device__ __forceinline__ v2f pk_fma(v2f a, v2f b, v2f c) {
    v2f d;
    asm("v_pk_fma_f32 %0, %1, %2, %3" : "=v"(d) : "v"(a), "v"(b), "v"(c));
    return d;
}
__device__ __forceinline__ v2f pk_add(v2f a, v2f b) {
    v2f d;
    asm("v_pk_add_f32 %0, %1, %2" : "=v"(d) : "v"(a), "v"(b));
    return d;
}

// ---- 16-lane all-reduce sum via DPP butterfly (4 VALU levels) --------------
__device__ __forceinline__ float red16(float x) {
    x += __int_as_float(__builtin_amdgcn_update_dpp(0, __float_as_int(x), 0xB1,  0xF, 0xF, true));
    x += __int_as_float(__builtin_amdgcn_update_dpp(0, __float_as_int(x), 0x4E,  0xF, 0xF, true));
    x += __int_as_float(__builtin_amdgcn_update_dpp(0, __float_as_int(x), 0x141, 0xF, 0xF, true));
    x += __int_as_float(__builtin_amdgcn_update_dpp(0, __float_as_int(x), 0x140, 0xF, 0xF, true));
    return x;
}

// ---------------------------------------------------------------------------
// Kernel 1: centered, gamma-folded W1 columns + 6 variance-quadratic scalars.
// ---------------------------------------------------------------------------
__global__ void prep_kernel(const float* __restrict__ W1,
                            const float* __restrict__ b1,
                            const float* __restrict__ gamma,
                            float* __restrict__ wsv,
                            float* __restrict__ wss) {
    __shared__ float r[6][128];
    const int t = threadIdx.x;  // 128 threads
    const float w0 = W1[t], w1 = W1[128 + t], bb = b1[t];
    r[0][t] = w0; r[1][t] = w1; r[2][t] = bb;
    __syncthreads();
    for (int s = 64; s > 0; s >>= 1) {
        if (t < s) { r[0][t] += r[0][t + s]; r[1][t] += r[1][t + s]; r[2][t] += r[2][t + s]; }
        __syncthreads();
    }
    const float m0 = r[0][0] * (1.f / 128.f);
    const float m1 = r[1][0] * (1.f / 128.f);
    const float mb = r[2][0] * (1.f / 128.f);
    __syncthreads();
    const float c0 = w0 - m0, c1 = w1 - m1, cb = bb - mb;
    const float g = gamma[t];
    wsv[t]       = g * c0;
    wsv[128 + t] = g * c1;
    wsv[256 + t] = g * cb;
    r[0][t] = c0 * c0; r[1][t] = c1 * c1; r[2][t] = cb * cb;
    r[3][t] = c0 * c1; r[4][t] = c0 * cb; r[5][t] = c1 * cb;
    __syncthreads();
    for (int s = 64; s > 0; s >>= 1) {
        if (t < s) {
            #pragma unroll
            for (int q = 0; q < 6; ++q) r[q][t] += r[q][t + s];
        }
        __syncthreads();
    }
    if (t < 6) wss[t] = r[t][0] * (1.f / 128.f);
}

// ---------------------------------------------------------------------------
// Kernel 1b: per-node triple (a,b,c) = rsqrt(var+eps) * (x0, x1, 1), float4.
// ---------------------------------------------------------------------------
__global__ __launch_bounds__(256) void triple_kernel(const float* __restrict__ X,
                                                     const float* __restrict__ wss,
                                                     float4* __restrict__ T) {
    const int gid = blockIdx.x * 256 + threadIdx.x;     // 0 .. B*N-1
    const float2 x = ((const float2*)X)[gid];
    const float S00 = wss[0], S11 = wss[1], Sbb = wss[2];
    const float S01 = wss[3], S0b = wss[4], S1b = wss[5];
    const float v = fmaf(x.x * x.x, S00, fmaf(x.y * x.y, S11, Sbb))
                  + 2.f * fmaf(x.x * x.y, S01, fmaf(x.x, S0b, x.y * S1b));
    const float rs = rsqrtf(v + LN_EPS);
    T[gid] = float4{rs * x.x, rs * x.y, rs, 0.f};
}

// ---------------------------------------------------------------------------
// Kernel 2: per-pair fused recompute, 4 pairs/wave, packed fp32, prefetched.
// 16-lane group per pair; sublane s owns d = s+32m (lo), s+32m+16 (hi).
// ---------------------------------------------------------------------------
__global__ __launch_bounds__(256, 4) void pair_kernel(
        const float4* __restrict__ T,
        const int*    __restrict__ pairs,
        const float*  __restrict__ wsv,
        const float*  __restrict__ beta,
        float* __restrict__ part) {
    const int chunk = blockIdx.x;
    const int b = blockIdx.y;
    const int tid = threadIdx.x;
    const int w = tid >> 6;      // wave id 0..3
    const int l = tid & 63;      // lane
    const int g = l >> 4;        // 16-lane group (pair slot in wave) 0..3
    const int s = l & 15;        // sublane = base d index

    // per-lane packed constants
    v2f gw0[4], gw1[4], gbc[4], be2[4];
    #pragma unroll
    for (int m = 0; m < 4; ++m) {
        const int d0 = s + 32 * m;
        gw0[m] = v2f{wsv[d0],        wsv[d0 + 16]};
        gw1[m] = v2f{wsv[128 + d0],  wsv[128 + d0 + 16]};
        gbc[m] = v2f{wsv[256 + d0],  wsv[256 + d0 + 16]};
        be2[m] = v2f{beta[d0],       beta[d0 + 16]};
    }
    const v2f neg1 = v2f{-1.f, -1.f};

    const float4* Tb = T + (size_t)b * N;
    const int2*   pr = (const int2*)pairs;

    v2f acc[4];
    #pragma unroll
    for (int m = 0; m < 4; ++m) acc[m] = v2f{0.f, 0.f};

    const int pbase = chunk * PPB;
    const int slot = w * 4 + g;          // 0..15 pairs per block-iteration

    // ---- software pipeline: 1-deep prefetch ----
    int2  ij = pr[pbase + slot];
    float4 ti = Tb[ij.x];
    float4 tj = Tb[ij.y];

    #pragma unroll 2
    for (int t = 0; t < NIT; ++t) {
        // prefetch next iteration (clamped address on last iter; uniform)
        const int pn = pbase + (t + 1 < NIT ? (t + 1) * 16 : t * 16) + slot;
        const int2  ij2 = pr[pn];
        const float4 ti2 = Tb[ij2.x];
        const float4 tj2 = Tb[ij2.y];

        const v2f ai = v2f{ti.x, ti.x}, bi = v2f{ti.y, ti.y}, ci = v2f{ti.z, ti.z};
        const v2f aj = v2f{tj.x, tj.x}, bj = v2f{tj.y, tj.y}, cj = v2f{tj.z, tj.z};

        v2f uu[4], vv[4];
        v2f nu2 = v2f{0.f, 0.f}, nv2 = v2f{0.f, 0.f};
        #pragma unroll
        for (int m = 0; m < 4; ++m) {
            // z = relu(a*w0 + b*w1 + c*wb + beta)
            const v2f hi = pk_fma(ai, gw0[m], pk_fma(bi, gw1[m], pk_fma(ci, gbc[m], be2[m])));
            const v2f hj = pk_fma(aj, gw0[m], pk_fma(bj, gw1[m], pk_fma(cj, gbc[m], be2[m])));
            const v2f za = v2f{fmaxf(hi.x, 0.f), fmaxf(hi.y, 0.f)};
            const v2f zb = v2f{fmaxf(hj.x, 0.f), fmaxf(hj.y, 0.f)};
            const v2f u = pk_fma(zb, neg1, za);   // za - zb
            const v2f v = pk_add(za, zb);         // za + zb
            nu2 = pk_fma(u, u, nu2);
            nv2 = pk_fma(v, v, nv2);
            uu[m] = u; vv[m] = v;
        }
        float nu = nu2.x + nu2.y;
        float nv = nv2.x + nv2.y;
        nu = red16(nu);
        nv = red16(nv);
        const float ru = rsqrtf(fmaxf(nu, 1e-24f));
        const float rv = rsqrtf(fmaxf(nv, 1e-24f));
        const v2f ru2 = v2f{ru, ru}, rv2 = v2f{rv, rv};
        #pragma unroll
        for (int m = 0; m < 4; ++m)
            acc[m] = pk_fma(uu[m], ru2, pk_fma(vv[m], rv2, acc[m]));

        ij = ij2; ti = ti2; tj = tj2;
    }

    // block reduce: 16 slots -> one 128-float partial (padded: no conflicts)
    __shared__ float red[16][8][17];
    #pragma unroll
    for (int m = 0; m < 4; ++m) {
        red[slot][2 * m    ][s] = acc[m].x;   // d = s + 32m
        red[slot][2 * m + 1][s] = acc[m].y;   // d = s + 32m + 16
    }
    __syncthreads();
    if (tid < 128) {
        const int ss = tid & 15, kk = tid >> 4;   // d = ss + 16*kk == tid
        float sum = 0.f;
        #pragma unroll
        for (int q = 0; q < 16; ++q) sum += red[q][kk][ss];
        part[((size_t)b * S_CHUNKS + chunk) * 128 + tid] = sum;
    }
}

// ---------------------------------------------------------------------------
// Kernel 3: reduce partials -> sdi, MLP head + mem logits. 256 threads/block.
// ---------------------------------------------------------------------------
__global__ __launch_bounds__(256) void head_kernel(
        const float* __restrict__ part,
        const float* __restrict__ Wm1, const float* __restrict__ bm1,
        const float* __restrict__ Wm2, const float* __restrict__ bm2,
        const float* __restrict__ mem,
        float* __restrict__ out_logits, float* __restrict__ out_sdi) {
    const int b = blockIdx.x;
    const int t = threadIdx.x;
    __shared__ float s[128];
    __shared__ float h[128];

    if (t < 128) {
        float sv = 0.f;
        #pragma unroll
        for (int k = 0; k < S_CHUNKS; ++k)
            sv += part[((size_t)b * S_CHUNKS + k) * 128 + t];
        sv *= (1.f / (2.f * P));
        s[t] = sv;
        out_sdi[(size_t)b * 128 + t] = sv;
    }
    __syncthreads();
    if (t < 128) {
        float a = bm1[t];
        for (int d = 0; d < 128; ++d) a = fmaf(s[d], Wm1[d * 128 + t], a);
        h[t] = fmaxf(a, 0.f);
    }
    __syncthreads();
    if (t < 16 * C) {                       // 160 threads: 16 lanes per class
        const int c = t >> 4, l = t & 15;
        float lg = 0.f;
        #pragma unroll
        for (int q = 0; q < 8; ++q) {
            const int d = l + 16 * q;
            lg = fmaf(s[d], mem[c * 128 + d], fmaf(h[d], Wm2[d * C + c], lg));
        }
        lg = red16(lg);
        if (l == 0) out_logits[(size_t)b * C + c] = lg + bm2[c];
    }
}

extern "C" void kernel_launch(void* const* d_in, const int* in_sizes, int n_in,
                              void* d_out, int out_size, void* d_ws, size_t ws_size,
                              hipStream_t stream) {
    const float* X     = (const float*)d_in[0];
    const int*   pairs = (const int*)  d_in[1];
    const float* W1    = (const float*)d_in[2];
    const float* b1    = (const float*)d_in[3];
    const float* gamma = (const float*)d_in[4];
    const float* beta  = (const float*)d_in[5];
    const float* Wm1   = (const float*)d_in[6];
    const float* bm1   = (const float*)d_in[7];
    const float* Wm2   = (const float*)d_in[8];
    const float* bm2   = (const float*)d_in[9];
    const float* mem   = (const float*)d_in[10];

    float* out = (float*)d_out;
    float* ws  = (float*)d_ws;
    float* wsv  = ws;                        // 384 floats
    float* wss  = ws + 384;                  // 6 floats (pad to 512)
    float4* T   = (float4*)(ws + 512);       // B*N float4 (8 MB)
    float* part = ws + 512 + (size_t)B * N * 4;  // B*S_CHUNKS*128 floats

    prep_kernel<<<1, 128, 0, stream>>>(W1, b1, gamma, wsv, wss);
    triple_kernel<<<(B * N) / 256, 256, 0, stream>>>(X, wss, T);
    pair_kernel<<<dim3(S_CHUNKS, B), 256, 0, stream>>>(T, pairs, wsv, beta, part);
    head_kernel<<<B, 256, 0, stream>>>(part, Wm1, bm1, Wm2, bm2, mem,
                                       out, out + (size_t)B * C);
}

// Round 6
// 46.831 us; speedup vs baseline: 1.1218x; 1.1218x over previous
//
#include <hip/hip_runtime.h>

#define B 256
#define N 2048
#define P 2048
#define C 10
#define S_CHUNKS 8
#define PPB (P / S_CHUNKS)     // 256 pairs per block
#define NIT (PPB / 32)         // 8 iterations; 32 pairs per block-iter
#define LN_EPS 1e-5f

typedef float v2f __attribute__((ext_vector_type(2)));

// ---- VOP3P packed fp32 (plain forms only -- proven in R3/R4) ---------------
static __device__ __forceinline__ v2f pk_fma(v2f a, v2f b, v2f c) {
    v2f d;
    asm("v_pk_fma_f32 %0, %1, %2, %3" : "=v"(d) : "v"(a), "v"(b), "v"(c));
    return d;
}
static __device__ __forceinline__ v2f pk_add(v2f a, v2f b) {
    v2f d;
    asm("v_pk_add_f32 %0, %1, %2" : "=v"(d) : "v"(a), "v"(b));
    return d;
}

// ---- 16-lane all-reduce sum via DPP butterfly ------------------------------
static __device__ __forceinline__ float red16(float x) {
    x += __int_as_float(__builtin_amdgcn_update_dpp(0, __float_as_int(x), 0xB1,  0xF, 0xF, true));
    x += __int_as_float(__builtin_amdgcn_update_dpp(0, __float_as_int(x), 0x4E,  0xF, 0xF, true));
    x += __int_as_float(__builtin_amdgcn_update_dpp(0, __float_as_int(x), 0x141, 0xF, 0xF, true));
    x += __int_as_float(__builtin_amdgcn_update_dpp(0, __float_as_int(x), 0x140, 0xF, 0xF, true));
    return x;
}

// ---------------------------------------------------------------------------
// Kernel 1 (merged prep+triple): every block redundantly reduces the 6
// variance-quadratic scalars from W1/b1; block 0 additionally writes the
// swizzled per-lane weight table; all blocks write the per-node triple
// T = rsqrt(var+eps) * (x0, x1, 1).
// ---------------------------------------------------------------------------
__global__ __launch_bounds__(256) void triple_kernel(
        const float* __restrict__ X,
        const float* __restrict__ W1, const float* __restrict__ b1,
        const float* __restrict__ gamma, const float* __restrict__ beta,
        float* __restrict__ wsw, float4* __restrict__ T) {
    const int t = threadIdx.x;
    __shared__ float r[6][128];
    __shared__ float sc[6];

    float w0 = 0.f, w1 = 0.f, bb = 0.f;
    if (t < 128) {
        w0 = W1[t]; w1 = W1[128 + t]; bb = b1[t];
        r[0][t] = w0; r[1][t] = w1; r[2][t] = bb;
    }
    __syncthreads();
    for (int s = 64; s > 0; s >>= 1) {
        if (t < s) { r[0][t] += r[0][t + s]; r[1][t] += r[1][t + s]; r[2][t] += r[2][t + s]; }
        __syncthreads();
    }
    const float m0 = r[0][0] * (1.f / 128.f);
    const float m1 = r[1][0] * (1.f / 128.f);
    const float mb = r[2][0] * (1.f / 128.f);
    __syncthreads();
    float c0 = 0.f, c1 = 0.f, cb = 0.f;
    if (t < 128) {
        c0 = w0 - m0; c1 = w1 - m1; cb = bb - mb;
        r[0][t] = c0 * c0; r[1][t] = c1 * c1; r[2][t] = cb * cb;
        r[3][t] = c0 * c1; r[4][t] = c0 * cb; r[5][t] = c1 * cb;
    }
    __syncthreads();
    for (int s = 64; s > 0; s >>= 1) {
        if (t < s) {
            #pragma unroll
            for (int q = 0; q < 6; ++q) r[q][t] += r[q][t + s];
        }
        __syncthreads();
    }
    if (t < 6) sc[t] = r[t][0] * (1.f / 128.f);
    __syncthreads();

    // block 0: swizzled weight table. d = s_ + 16*half + 32*m
    if (blockIdx.x == 0 && t < 128) {
        const float g = gamma[t];
        const int s_ = t & 15, half = (t >> 4) & 1, m = t >> 5;
        float* dst = wsw + s_ * 32 + m * 8;
        dst[0 + half] = g * c0;
        dst[2 + half] = g * c1;
        dst[4 + half] = g * cb;
        dst[6 + half] = beta[t];
    }

    const float S00 = sc[0], S11 = sc[1], Sbb = sc[2];
    const float S01 = sc[3], S0b = sc[4], S1b = sc[5];
    const int gid = blockIdx.x * 256 + t;       // 0 .. B*N-1
    const float2 x = ((const float2*)X)[gid];
    const float v = fmaf(x.x * x.x, S00, fmaf(x.y * x.y, S11, Sbb))
                  + 2.f * fmaf(x.x * x.y, S01, fmaf(x.x, S0b, x.y * S1b));
    const float rs = rsqrtf(v + LN_EPS);
    T[gid] = float4{rs * x.x, rs * x.y, rs, 0.f};
}

// ---------------------------------------------------------------------------
// Kernel 2: per-pair fused recompute. 16-lane group handles 2 pair-streams
// per iteration (8 pairs/wave-iter); sublane s owns d = s+32m (lo), +16 (hi).
// Index prefetch 1 iter ahead; stream-A data prefetch 1 iter ahead.
// ---------------------------------------------------------------------------
__global__ __launch_bounds__(256) void pair_kernel(
        const float4* __restrict__ T,
        const int*    __restrict__ pairs,
        const float*  __restrict__ wsw,
        float* __restrict__ part) {
    const int b = blockIdx.x;
    const int chunk = blockIdx.y;
    const int tid = threadIdx.x;
    const int w = tid >> 6, l = tid & 63, g = l >> 4, s = l & 15;
    const int slot = w * 4 + g;      // 0..15

    // per-lane packed weights from swizzled table: 8x dwordx4
    const float4* Wl = (const float4*)(wsw + s * 32);
    v2f gw0[4], gw1[4], gbc[4], be2[4];
    #pragma unroll
    for (int m = 0; m < 4; ++m) {
        const float4 a = Wl[2 * m], c = Wl[2 * m + 1];
        gw0[m] = v2f{a.x, a.y}; gw1[m] = v2f{a.z, a.w};
        gbc[m] = v2f{c.x, c.y}; be2[m] = v2f{c.z, c.w};
    }
    const v2f neg1 = v2f{-1.f, -1.f};

    const float4* Tb  = T + (size_t)b * N;
    const int4*   pr4 = (const int4*)pairs;      // 2 pairs per int4
    const int i4base  = chunk * (PPB / 2);

    v2f acc[4];
    #pragma unroll
    for (int m = 0; m < 4; ++m) acc[m] = v2f{0.f, 0.f};

    auto proc = [&](const float4 ti, const float4 tj) {
        const v2f ai = v2f{ti.x, ti.x}, bi = v2f{ti.y, ti.y}, ci = v2f{ti.z, ti.z};
        const v2f aj = v2f{tj.x, tj.x}, bj = v2f{tj.y, tj.y}, cj = v2f{tj.z, tj.z};
        v2f uu[4], vv[4];
        v2f nu2 = v2f{0.f, 0.f}, nv2 = v2f{0.f, 0.f};
        #pragma unroll
        for (int m = 0; m < 4; ++m) {
            const v2f hi = pk_fma(ai, gw0[m], pk_fma(bi, gw1[m], pk_fma(ci, gbc[m], be2[m])));
            const v2f hj = pk_fma(aj, gw0[m], pk_fma(bj, gw1[m], pk_fma(cj, gbc[m], be2[m])));
            const v2f za = v2f{fmaxf(hi.x, 0.f), fmaxf(hi.y, 0.f)};
            const v2f zb = v2f{fmaxf(hj.x, 0.f), fmaxf(hj.y, 0.f)};
            const v2f u = pk_fma(zb, neg1, za);   // za - zb
            const v2f v = pk_add(za, zb);         // za + zb
            nu2 = pk_fma(u, u, nu2);
            nv2 = pk_fma(v, v, nv2);
            uu[m] = u; vv[m] = v;
        }
        const float nu = red16(nu2.x + nu2.y);
        const float nv = red16(nv2.x + nv2.y);
        const float ru = rsqrtf(fmaxf(nu, 1e-24f));
        const float rv = rsqrtf(fmaxf(nv, 1e-24f));
        const v2f ru2 = v2f{ru, ru}, rv2 = v2f{rv, rv};
        #pragma unroll
        for (int m = 0; m < 4; ++m)
            acc[m] = pk_fma(uu[m], ru2, pk_fma(vv[m], rv2, acc[m]));
    };

    // software pipeline: idx prefetched 1 iter; stream-A data prefetched
    int4 idx = pr4[i4base + slot];
    float4 tiA = Tb[idx.x], tjA = Tb[idx.y];

    for (int t = 0; t < NIT; ++t) {
        const float4 tiB = Tb[idx.z], tjB = Tb[idx.w];
        int4 nidx = idx;
        if (t + 1 < NIT) nidx = pr4[i4base + (t + 1) * 16 + slot];

        proc(tiA, tjA);                          // stream A (prefetched data)

        const float4 ntiA = Tb[nidx.x], ntjA = Tb[nidx.y];  // next A data

        proc(tiB, tjB);                          // stream B (loads hidden under A)

        idx = nidx; tiA = ntiA; tjA = ntjA;
    }

    // block reduce: 16 slots -> one 128-float partial (padded: conflict-free)
    __shared__ float red[16][8][17];
    #pragma unroll
    for (int m = 0; m < 4; ++m) {
        red[slot][2 * m    ][s] = acc[m].x;   // d = s + 32m
        red[slot][2 * m + 1][s] = acc[m].y;   // d = s + 32m + 16
    }
    __syncthreads();
    if (tid < 128) {
        const int ss = tid & 15, kk = tid >> 4;   // d = ss + 16*kk == tid
        float sum = 0.f;
        #pragma unroll
        for (int q = 0; q < 16; ++q) sum += red[q][kk][ss];
        part[((size_t)b * S_CHUNKS + chunk) * 128 + tid] = sum;
    }
}

// ---------------------------------------------------------------------------
// Kernel 3: reduce partials -> sdi, MLP head + mem logits.
// ---------------------------------------------------------------------------
__global__ __launch_bounds__(256) void head_kernel(
        const float* __restrict__ part,
        const float* __restrict__ Wm1, const float* __restrict__ bm1,
        const float* __restrict__ Wm2, const float* __restrict__ bm2,
        const float* __restrict__ mem,
        float* __restrict__ out_logits, float* __restrict__ out_sdi) {
    const int b = blockIdx.x;
    const int t = threadIdx.x;
    __shared__ float s[128];
    __shared__ float h[128];

    if (t < 128) {
        float sv = 0.f;
        #pragma unroll
        for (int k = 0; k < S_CHUNKS; ++k)
            sv += part[((size_t)b * S_CHUNKS + k) * 128 + t];
        sv *= (1.f / (2.f * P));
        s[t] = sv;
        out_sdi[(size_t)b * 128 + t] = sv;
    }
    __syncthreads();
    if (t < 128) {
        float a = bm1[t];
        for (int d = 0; d < 128; ++d) a = fmaf(s[d], Wm1[d * 128 + t], a);
        h[t] = fmaxf(a, 0.f);
    }
    __syncthreads();
    if (t < 16 * C) {                       // 160 threads: 16 lanes per class
        const int c = t >> 4, l = t & 15;
        float lg = 0.f;
        #pragma unroll
        for (int q = 0; q < 8; ++q) {
            const int d = l + 16 * q;
            lg = fmaf(s[d], mem[c * 128 + d], fmaf(h[d], Wm2[d * C + c], lg));
        }
        lg = red16(lg);
        if (l == 0) out_logits[(size_t)b * C + c] = lg + bm2[c];
    }
}

extern "C" void kernel_launch(void* const* d_in, const int* in_sizes, int n_in,
                              void* d_out, int out_size, void* d_ws, size_t ws_size,
                              hipStream_t stream) {
    const float* X     = (const float*)d_in[0];
    const int*   pairs = (const int*)  d_in[1];
    const float* W1    = (const float*)d_in[2];
    const float* b1    = (const float*)d_in[3];
    const float* gamma = (const float*)d_in[4];
    const float* beta  = (const float*)d_in[5];
    const float* Wm1   = (const float*)d_in[6];
    const float* bm1   = (const float*)d_in[7];
    const float* Wm2   = (const float*)d_in[8];
    const float* bm2   = (const float*)d_in[9];
    const float* mem   = (const float*)d_in[10];

    float* out = (float*)d_out;
    float* ws  = (float*)d_ws;
    float*  wsw  = ws;                           // 512 floats, swizzled weights
    float4* T    = (float4*)(ws + 512);          // B*N float4 (8 MB)
    float*  part = ws + 512 + (size_t)B * N * 4; // B*S_CHUNKS*128 floats

    triple_kernel<<<(B * N) / 256, 256, 0, stream>>>(X, W1, b1, gamma, beta, wsw, T);
    pair_kernel<<<dim3(B, S_CHUNKS), 256, 0, stream>>>(T, pairs, wsw, part);
    head_kernel<<<B, 256, 0, stream>>>(part, Wm1, bm1, Wm2, bm2, mem,
                                       out, out + (size_t)B * C);
}

// Round 7
// 46.289 us; speedup vs baseline: 1.1349x; 1.0117x over previous
//
#include <hip/hip_runtime.h>

#define B 256
#define N 2048
#define P 2048
#define C 10
#define NG 64                  // 16-lane groups per block (16 waves x 4)
#define NIT (P / (NG * 2))     // 16 iterations; 2 pair-streams per group
#define LN_EPS 1e-5f

typedef float v2f __attribute__((ext_vector_type(2)));

// ---- VOP3P packed fp32 (plain forms only -- proven R3/R4/R6) ---------------
static __device__ __forceinline__ v2f pk_fma(v2f a, v2f b, v2f c) {
    v2f d;
    asm("v_pk_fma_f32 %0, %1, %2, %3" : "=v"(d) : "v"(a), "v"(b), "v"(c));
    return d;
}
static __device__ __forceinline__ v2f pk_add(v2f a, v2f b) {
    v2f d;
    asm("v_pk_add_f32 %0, %1, %2" : "=v"(d) : "v"(a), "v"(b));
    return d;
}

// ---- 16-lane all-reduce sum via DPP butterfly (proven R2..R6) --------------
static __device__ __forceinline__ float red16(float x) {
    x += __int_as_float(__builtin_amdgcn_update_dpp(0, __float_as_int(x), 0xB1,  0xF, 0xF, true));
    x += __int_as_float(__builtin_amdgcn_update_dpp(0, __float_as_int(x), 0x4E,  0xF, 0xF, true));
    x += __int_as_float(__builtin_amdgcn_update_dpp(0, __float_as_int(x), 0x141, 0xF, 0xF, true));
    x += __int_as_float(__builtin_amdgcn_update_dpp(0, __float_as_int(x), 0x140, 0xF, 0xF, true));
    return x;
}

// ---------------------------------------------------------------------------
// Kernel 1 (merged prep+triple, unchanged from R6): every block redundantly
// reduces the 6 variance-quadratic scalars; block 0 writes the swizzled
// per-lane weight table; all blocks write T = rsqrt(var+eps) * (x0, x1, 1).
// ---------------------------------------------------------------------------
__global__ __launch_bounds__(256) void triple_kernel(
        const float* __restrict__ X,
        const float* __restrict__ W1, const float* __restrict__ b1,
        const float* __restrict__ gamma, const float* __restrict__ beta,
        float* __restrict__ wsw, float4* __restrict__ T) {
    const int t = threadIdx.x;
    __shared__ float r[6][128];
    __shared__ float sc[6];

    float w0 = 0.f, w1 = 0.f, bb = 0.f;
    if (t < 128) {
        w0 = W1[t]; w1 = W1[128 + t]; bb = b1[t];
        r[0][t] = w0; r[1][t] = w1; r[2][t] = bb;
    }
    __syncthreads();
    for (int s = 64; s > 0; s >>= 1) {
        if (t < s) { r[0][t] += r[0][t + s]; r[1][t] += r[1][t + s]; r[2][t] += r[2][t + s]; }
        __syncthreads();
    }
    const float m0 = r[0][0] * (1.f / 128.f);
    const float m1 = r[1][0] * (1.f / 128.f);
    const float mb = r[2][0] * (1.f / 128.f);
    __syncthreads();
    float c0 = 0.f, c1 = 0.f, cb = 0.f;
    if (t < 128) {
        c0 = w0 - m0; c1 = w1 - m1; cb = bb - mb;
        r[0][t] = c0 * c0; r[1][t] = c1 * c1; r[2][t] = cb * cb;
        r[3][t] = c0 * c1; r[4][t] = c0 * cb; r[5][t] = c1 * cb;
    }
    __syncthreads();
    for (int s = 64; s > 0; s >>= 1) {
        if (t < s) {
            #pragma unroll
            for (int q = 0; q < 6; ++q) r[q][t] += r[q][t + s];
        }
        __syncthreads();
    }
    if (t < 6) sc[t] = r[t][0] * (1.f / 128.f);
    __syncthreads();

    if (blockIdx.x == 0 && t < 128) {
        const float g = gamma[t];
        const int s_ = t & 15, half = (t >> 4) & 1, m = t >> 5;
        float* dst = wsw + s_ * 32 + m * 8;
        dst[0 + half] = g * c0;
        dst[2 + half] = g * c1;
        dst[4 + half] = g * cb;
        dst[6 + half] = beta[t];
    }

    const float S00 = sc[0], S11 = sc[1], Sbb = sc[2];
    const float S01 = sc[3], S0b = sc[4], S1b = sc[5];
    const int gid = blockIdx.x * 256 + t;       // 0 .. B*N-1
    const float2 x = ((const float2*)X)[gid];
    const float v = fmaf(x.x * x.x, S00, fmaf(x.y * x.y, S11, Sbb))
                  + 2.f * fmaf(x.x * x.y, S01, fmaf(x.x, S0b, x.y * S1b));
    const float rs = rsqrtf(v + LN_EPS);
    T[gid] = float4{rs * x.x, rs * x.y, rs, 0.f};
}

// ---------------------------------------------------------------------------
// Kernel 2: one block per batch, 1024 threads (16 waves, 64 groups).
// T slice staged in LDS (32 KB); group handles 2 pair-streams per iter.
// Writes final scaled sdi for its batch directly to out_sdi.
// ---------------------------------------------------------------------------
__global__ __launch_bounds__(1024, 4) void pair_kernel(
        const float4* __restrict__ T,
        const int*    __restrict__ pairs,
        const float*  __restrict__ wsw,
        float* __restrict__ out_sdi) {
    const int b = blockIdx.x;
    const int tid = threadIdx.x;
    const int w = tid >> 6, l = tid & 63, g = l >> 4, s = l & 15;
    const int slot = w * 4 + g;      // 0..63

    // 34816 B: first 32 KB = staged T, whole buffer reused as reduce scratch
    __shared__ __align__(16) float ldsbuf[NG * 136];
    float4* Tl = (float4*)ldsbuf;

    // stage T_b: 2048 float4, coalesced, 2 per thread
    const float4* Tb = T + (size_t)b * N;
    Tl[tid]        = Tb[tid];
    Tl[tid + 1024] = Tb[tid + 1024];

    // per-lane packed weights from swizzled table: 8x dwordx4 (independent of LDS)
    const float4* Wl = (const float4*)(wsw + s * 32);
    v2f gw0[4], gw1[4], gbc[4], be2[4];
    #pragma unroll
    for (int m = 0; m < 4; ++m) {
        const float4 a = Wl[2 * m], c = Wl[2 * m + 1];
        gw0[m] = v2f{a.x, a.y}; gw1[m] = v2f{a.z, a.w};
        gbc[m] = v2f{c.x, c.y}; be2[m] = v2f{c.z, c.w};
    }
    const v2f neg1 = v2f{-1.f, -1.f};

    const int4* pr4 = (const int4*)pairs;      // 2 pairs per int4, 1024 total
    int4 idx = pr4[slot];                      // global load, pre-sync OK

    v2f acc[4];
    #pragma unroll
    for (int m = 0; m < 4; ++m) acc[m] = v2f{0.f, 0.f};

    auto proc = [&](const float4 ti, const float4 tj) {
        const v2f ai = v2f{ti.x, ti.x}, bi = v2f{ti.y, ti.y}, ci = v2f{ti.z, ti.z};
        const v2f aj = v2f{tj.x, tj.x}, bj = v2f{tj.y, tj.y}, cj = v2f{tj.z, tj.z};
        v2f uu[4], vv[4];
        v2f nu2 = v2f{0.f, 0.f}, nv2 = v2f{0.f, 0.f};
        #pragma unroll
        for (int m = 0; m < 4; ++m) {
            const v2f hi = pk_fma(ai, gw0[m], pk_fma(bi, gw1[m], pk_fma(ci, gbc[m], be2[m])));
            const v2f hj = pk_fma(aj, gw0[m], pk_fma(bj, gw1[m], pk_fma(cj, gbc[m], be2[m])));
            const v2f za = v2f{fmaxf(hi.x, 0.f), fmaxf(hi.y, 0.f)};
            const v2f zb = v2f{fmaxf(hj.x, 0.f), fmaxf(hj.y, 0.f)};
            const v2f u = pk_fma(zb, neg1, za);   // za - zb
            const v2f v = pk_add(za, zb);         // za + zb
            nu2 = pk_fma(u, u, nu2);
            nv2 = pk_fma(v, v, nv2);
            uu[m] = u; vv[m] = v;
        }
        const float nu = red16(nu2.x + nu2.y);
        const float nv = red16(nv2.x + nv2.y);
        const float ru = rsqrtf(fmaxf(nu, 1e-24f));
        const float rv = rsqrtf(fmaxf(nv, 1e-24f));
        const v2f ru2 = v2f{ru, ru}, rv2 = v2f{rv, rv};
        #pragma unroll
        for (int m = 0; m < 4; ++m)
            acc[m] = pk_fma(uu[m], ru2, pk_fma(vv[m], rv2, acc[m]));
    };

    __syncthreads();                           // T staged

    float4 tiA = Tl[idx.x], tjA = Tl[idx.y];

    for (int t = 0; t < NIT; ++t) {
        const float4 tiB = Tl[idx.z], tjB = Tl[idx.w];
        int4 nidx = idx;
        if (t + 1 < NIT) nidx = pr4[(t + 1) * NG + slot];

        proc(tiA, tjA);                        // stream A

        const float4 ntiA = Tl[nidx.x], ntjA = Tl[nidx.y];

        proc(tiB, tjB);                        // stream B

        idx = nidx; tiA = ntiA; tjA = ntjA;
    }

    __syncthreads();                           // done reading staged T

    // reduce scratch overlays the staging buffer: slot-major [64][8][17]
    #pragma unroll
    for (int m = 0; m < 4; ++m) {
        ldsbuf[slot * 136 + (2 * m)     * 17 + s] = acc[m].x;   // d = s + 32m
        ldsbuf[slot * 136 + (2 * m + 1) * 17 + s] = acc[m].y;   // d = s + 32m + 16
    }
    __syncthreads();
    if (tid < 128) {
        const int ss = tid & 15, kk = tid >> 4;   // d = ss + 16*kk == tid
        float sum = 0.f;
        #pragma unroll 8
        for (int q = 0; q < NG; ++q) sum += ldsbuf[q * 136 + kk * 17 + ss];
        out_sdi[(size_t)b * 128 + tid] = sum * (1.f / (2.f * P));
    }
}

// ---------------------------------------------------------------------------
// Kernel 3: MLP head + mem logits; sdi comes pre-reduced from pair_kernel.
// ---------------------------------------------------------------------------
__global__ __launch_bounds__(256) void head_kernel(
        const float* __restrict__ sdi,
        const float* __restrict__ Wm1, const float* __restrict__ bm1,
        const float* __restrict__ Wm2, const float* __restrict__ bm2,
        const float* __restrict__ mem,
        float* __restrict__ out_logits) {
    const int b = blockIdx.x;
    const int t = threadIdx.x;
    __shared__ float s[128];
    __shared__ float h[128];

    if (t < 128) s[t] = sdi[(size_t)b * 128 + t];
    __syncthreads();
    if (t < 128) {
        float a = bm1[t];
        for (int d = 0; d < 128; ++d) a = fmaf(s[d], Wm1[d * 128 + t], a);
        h[t] = fmaxf(a, 0.f);
    }
    __syncthreads();
    if (t < 16 * C) {                       // 160 threads: 16 lanes per class
        const int c = t >> 4, l = t & 15;
        float lg = 0.f;
        #pragma unroll
        for (int q = 0; q < 8; ++q) {
            const int d = l + 16 * q;
            lg = fmaf(s[d], mem[c * 128 + d], fmaf(h[d], Wm2[d * C + c], lg));
        }
        lg = red16(lg);
        if (l == 0) out_logits[(size_t)b * C + c] = lg + bm2[c];
    }
}

extern "C" void kernel_launch(void* const* d_in, const int* in_sizes, int n_in,
                              void* d_out, int out_size, void* d_ws, size_t ws_size,
                              hipStream_t stream) {
    const float* X     = (const float*)d_in[0];
    const int*   pairs = (const int*)  d_in[1];
    const float* W1    = (const float*)d_in[2];
    const float* b1    = (const float*)d_in[3];
    const float* gamma = (const float*)d_in[4];
    const float* beta  = (const float*)d_in[5];
    const float* Wm1   = (const float*)d_in[6];
    const float* bm1   = (const float*)d_in[7];
    const float* Wm2   = (const float*)d_in[8];
    const float* bm2   = (const float*)d_in[9];
    const float* mem   = (const float*)d_in[10];

    float* out_logits = (float*)d_out;                 // B*C
    float* out_sdi    = (float*)d_out + (size_t)B * C; // B*128
    float* ws  = (float*)d_ws;
    float*  wsw = ws;                        // 512 floats, swizzled weights
    float4* T   = (float4*)(ws + 512);       // B*N float4 (8 MB)

    triple_kernel<<<(B * N) / 256, 256, 0, stream>>>(X, W1, b1, gamma, beta, wsw, T);
    pair_kernel<<<B, 1024, 0, stream>>>(T, pairs, wsw, out_sdi);
    head_kernel<<<B, 256, 0, stream>>>(out_sdi, Wm1, bm1, Wm2, bm2, mem, out_logits);
}